// Round 1
// baseline (1599.348 us; speedup 1.0000x reference)
//
#include <hip/hip_runtime.h>
#include <hip/hip_bf16.h>
#include <stdint.h>

typedef __hip_bfloat16 bf16_t;
typedef __attribute__((ext_vector_type(4))) float f32x4;
typedef __attribute__((ext_vector_type(8))) short bf16x8;
typedef __attribute__((ext_vector_type(4))) int int4v;

#define D_MODEL 1024
#define D_INNER 2048
#define D_STATE 16
#define DT_RANK 64
#define BATCH   2
#define SEQLEN  2048
#define KPAD    1056   // 1025 padded up to multiple of 32

// ---------------- convert f32 -> bf16 with optional right-pad (zeros) -------
__global__ void k_convert_pad(const float* __restrict__ src, bf16_t* __restrict__ dst,
                              int rows, int cols, int dcols)
{
    long long idx = (long long)blockIdx.x * blockDim.x + threadIdx.x;
    long long total = (long long)rows * dcols;
    if (idx >= total) return;
    int c = (int)(idx % dcols);
    long long r = idx / dcols;
    float v = (c < cols) ? src[r * (long long)cols + c] : 0.0f;
    dst[idx] = __float2bfloat16(v);
}

// ---------------- bf16 MFMA GEMM: C[M,N] = A[M,K] * B[N,K]^T ----------------
// A,B bf16 row-major (K contiguous). 128x128 block tile, 4 waves (2x2),
// each wave 64x64 = 4x4 frags of 16x16, BK=32 (one mfma_16x16x32 per frag).
template<bool OUT_BF16>
__global__ __launch_bounds__(256)
void k_gemm(const bf16_t* __restrict__ A, const bf16_t* __restrict__ B,
            void* __restrict__ Cv,
            int M, int N, int K, int lda, int ldb, int ldc,
            long long strideA, long long strideB, long long strideC)
{
    const bf16_t* Ab = A + (long long)blockIdx.z * strideA;
    const bf16_t* Bb = B + (long long)blockIdx.z * strideB;

    __shared__ bf16_t As[128][40];   // +8 pad: row stride 80B (16B-aligned)
    __shared__ bf16_t Bs[128][40];

    const int tid  = threadIdx.x;
    const int lane = tid & 63;
    const int wave = tid >> 6;
    const int wm = (wave >> 1) * 64;
    const int wn = (wave & 1) * 64;
    const int bm = blockIdx.x * 128;
    const int bn = blockIdx.y * 128;

    const int srow = tid >> 2;          // 0..63
    const int sseg = (tid & 3) * 8;     // 0,8,16,24 (elements)

    f32x4 acc[4][4] = {};

    for (int k0 = 0; k0 < K; k0 += 32) {
        #pragma unroll
        for (int rr = 0; rr < 128; rr += 64) {
            int row = srow + rr;
            int ga = bm + row;
            int4v va = {0, 0, 0, 0};
            if (ga < M) va = *(const int4v*)(Ab + (long long)ga * lda + k0 + sseg);
            *(int4v*)(&As[row][sseg]) = va;
            int gb = bn + row;
            int4v vb = {0, 0, 0, 0};
            if (gb < N) vb = *(const int4v*)(Bb + (long long)gb * ldb + k0 + sseg);
            *(int4v*)(&Bs[row][sseg]) = vb;
        }
        __syncthreads();

        const int fr = lane & 15;
        const int fk = (lane >> 4) * 8;
        bf16x8 af[4], bfv[4];
        #pragma unroll
        for (int m = 0; m < 4; ++m)
            af[m] = *(const bf16x8*)(&As[wm + m * 16 + fr][fk]);
        #pragma unroll
        for (int n = 0; n < 4; ++n)
            bfv[n] = *(const bf16x8*)(&Bs[wn + n * 16 + fr][fk]);
        #pragma unroll
        for (int m = 0; m < 4; ++m)
            #pragma unroll
            for (int n = 0; n < 4; ++n)
                acc[m][n] = __builtin_amdgcn_mfma_f32_16x16x32_bf16(af[m], bfv[n], acc[m][n], 0, 0, 0);
        __syncthreads();
    }

    const int fr = lane & 15;
    const int rq = (lane >> 4) * 4;
    #pragma unroll
    for (int m = 0; m < 4; ++m) {
        #pragma unroll
        for (int n = 0; n < 4; ++n) {
            int col = bn + wn + n * 16 + fr;
            if (col >= N) continue;
            int rowb = bm + wm + m * 16 + rq;
            #pragma unroll
            for (int r = 0; r < 4; ++r) {
                long long off = (long long)blockIdx.z * strideC + (long long)(rowb + r) * ldc + col;
                if (OUT_BF16) ((bf16_t*)Cv)[off] = __float2bfloat16(acc[m][n][r]);
                else          ((float*)Cv)[off]  = acc[m][n][r];
            }
        }
    }
}

// ---------------- depthwise causal conv1d (k=4) + SiLU ----------------------
__global__ void k_conv(const float* __restrict__ xz, const float* __restrict__ cw,
                       const float* __restrict__ cb, float* __restrict__ xc)
{
    long long idx = (long long)blockIdx.x * 256 + threadIdx.x;
    int t = (int)(idx & (SEQLEN - 1));
    int d = (int)((idx >> 11) & (D_INNER - 1));
    int b = (int)(idx >> 22);
    const float* xp = xz + ((long long)b * 2 * D_INNER + d) * SEQLEN;
    float a = cb[d];
    const float* w = cw + d * 4;
    #pragma unroll
    for (int j = 0; j < 4; ++j) {
        int tt = t + j - 3;
        float xv = (tt >= 0) ? xp[tt] : 0.0f;
        a = fmaf(w[j], xv, a);
    }
    xc[idx] = a / (1.0f + __expf(-a));   // SiLU
}

// ---------------- transpose (b,d,l) f32 -> (b,l,d) bf16 ---------------------
__global__ void k_transpose_bf16(const float* __restrict__ src, bf16_t* __restrict__ dst)
{
    __shared__ float tile[64][65];
    const int b  = blockIdx.z;
    const int d0 = blockIdx.x * 64;
    const int l0 = blockIdx.y * 64;
    const int tl = threadIdx.x & 63;
    const int tr = threadIdx.x >> 6;   // 0..3
    #pragma unroll
    for (int i = 0; i < 64; i += 4)
        tile[tr + i][tl] = src[((long long)b * D_INNER + d0 + tr + i) * SEQLEN + l0 + tl];
    __syncthreads();
    #pragma unroll
    for (int i = 0; i < 64; i += 4)
        dst[((long long)b * SEQLEN + l0 + tr + i) * D_INNER + d0 + tl] =
            __float2bfloat16(tile[tl][tr + i]);
}

// ---------------- gate: y_g(b,l,d) bf16 = (y + D*xc) * silu(z) --------------
__global__ void k_gate(const float* __restrict__ y, const float* __restrict__ xc,
                       const float* __restrict__ xz, const float* __restrict__ Dp,
                       bf16_t* __restrict__ dst)
{
    __shared__ float tile[64][65];
    const int b  = blockIdx.z;
    const int d0 = blockIdx.x * 64;
    const int l0 = blockIdx.y * 64;
    const int tl = threadIdx.x & 63;
    const int tr = threadIdx.x >> 6;
    #pragma unroll
    for (int i = 0; i < 64; i += 4) {
        int d = d0 + tr + i;
        long long off = ((long long)b * D_INNER + d) * SEQLEN + l0 + tl;
        float yv = y[off] + Dp[d] * xc[off];
        float zv = xz[((long long)b * 2 * D_INNER + D_INNER + d) * SEQLEN + l0 + tl];
        tile[tr + i][tl] = yv * (zv / (1.0f + __expf(-zv)));
    }
    __syncthreads();
    #pragma unroll
    for (int i = 0; i < 64; i += 4)
        dst[((long long)b * SEQLEN + l0 + tr + i) * D_INNER + d0 + tl] =
            __float2bfloat16(tile[tl][tr + i]);
}

// ---------------- selective scan: 16 lanes per (b,d) channel ----------------
// h[n]_{t} = h[n]_{t-1} * exp(dt*A[n]) + dt*u*B[t,n];  y_t = sum_n h[n]*C[t,n]
__global__ __launch_bounds__(256)
void k_scan(const float* __restrict__ delta_in, float* __restrict__ y_out,
            const float* __restrict__ xc, const bf16_t* __restrict__ xdbl,
            const float* __restrict__ b_dt, const float* __restrict__ A_log)
{
    const int g = threadIdx.x >> 4;
    const int n = threadIdx.x & 15;
    const int c = blockIdx.x * 16 + g;        // channel id
    const int b = c >> 11;
    const int d = c & (D_INNER - 1);

    const float An  = -__expf(A_log[d * D_STATE + n]);
    const float bdt = b_dt[d];
    const long long chan = ((long long)b * D_INNER + d) * SEQLEN;
    const float* dp = delta_in + chan;
    const float* up = xc + chan;
    float* yp = y_out + chan;
    const bf16_t* bc = xdbl + (long long)b * SEQLEN * 96;

    float h = 0.0f;
    float ykeep = 0.0f;
    for (int t = 0; t < SEQLEN; ++t) {
        float draw = dp[t] + bdt;
        float dt = fmaxf(draw, 0.0f) + log1pf(__expf(-fabsf(draw)));  // softplus
        float u  = up[t];
        float Bn = __bfloat162float(bc[(long long)t * 96 + 64 + n]);
        float Cn = __bfloat162float(bc[(long long)t * 96 + 80 + n]);
        float dA = __expf(dt * An);
        h = fmaf(h, dA, dt * u * Bn);
        float yv = h * Cn;
        yv += __shfl_xor(yv, 1);
        yv += __shfl_xor(yv, 2);
        yv += __shfl_xor(yv, 4);
        yv += __shfl_xor(yv, 8);
        if ((t & 15) == n) ykeep = yv;          // park this t's row-sum
        if ((t & 15) == 15) yp[(t & ~15) + n] = ykeep;  // coalesced flush
    }
}

// ---------------------------------------------------------------------------
extern "C" void kernel_launch(void* const* d_in, const int* in_sizes, int n_in,
                              void* d_out, int out_size, void* d_ws, size_t ws_size,
                              hipStream_t stream)
{
    const float* hs   = (const float*)d_in[0];
    const float* Win  = (const float*)d_in[1];
    const float* cw   = (const float*)d_in[2];
    const float* cb   = (const float*)d_in[3];
    const float* Wx   = (const float*)d_in[4];
    const float* Wdt  = (const float*)d_in[5];
    const float* bdt  = (const float*)d_in[6];
    const float* Alog = (const float*)d_in[7];
    const float* Dp   = (const float*)d_in[8];
    const float* Wout = (const float*)d_in[9];
    float* out = (float*)d_out;

    char* w = (char*)d_ws;
    auto alloc = [&](long long bytes) {
        char* p = w;
        w += (bytes + 255) & ~255LL;
        return p;
    };
    bf16_t* hs_bf   = (bf16_t*)alloc((long long)BATCH * SEQLEN * KPAD * 2);
    bf16_t* win_bf  = (bf16_t*)alloc((long long)2 * D_INNER * KPAD * 2);
    bf16_t* wx_bf   = (bf16_t*)alloc((long long)96 * D_INNER * 2);
    bf16_t* wdt_bf  = (bf16_t*)alloc((long long)D_INNER * DT_RANK * 2);
    bf16_t* wout_bf = (bf16_t*)alloc((long long)D_MODEL * D_INNER * 2);
    float*  xz      = (float*) alloc((long long)BATCH * 2 * D_INNER * SEQLEN * 4);
    float*  xc      = (float*) alloc((long long)BATCH * D_INNER * SEQLEN * 4);
    bf16_t* xct     = (bf16_t*)alloc((long long)BATCH * SEQLEN * D_INNER * 2); // reused as y_g
    bf16_t* xdbl    = (bf16_t*)alloc((long long)BATCH * SEQLEN * 96 * 2);
    float*  delta   = (float*) alloc((long long)BATCH * D_INNER * SEQLEN * 4); // reused as y (in-place)

    // --- prep converts (f32 -> bf16, K-pad with zeros) ---
    {
        long long tot = (long long)BATCH * SEQLEN * KPAD;
        k_convert_pad<<<(unsigned)((tot + 255) / 256), 256, 0, stream>>>(hs, hs_bf, BATCH * SEQLEN, 1025, KPAD);
    }
    {
        long long tot = (long long)2 * D_INNER * KPAD;
        k_convert_pad<<<(unsigned)((tot + 255) / 256), 256, 0, stream>>>(Win, win_bf, 2 * D_INNER, 1025, KPAD);
    }
    {
        long long tot = (long long)96 * D_INNER;
        k_convert_pad<<<(unsigned)((tot + 255) / 256), 256, 0, stream>>>(Wx, wx_bf, 96, D_INNER, D_INNER);
    }
    {
        long long tot = (long long)D_INNER * DT_RANK;
        k_convert_pad<<<(unsigned)((tot + 255) / 256), 256, 0, stream>>>(Wdt, wdt_bf, D_INNER, DT_RANK, DT_RANK);
    }
    {
        long long tot = (long long)D_MODEL * D_INNER;
        k_convert_pad<<<(unsigned)((tot + 255) / 256), 256, 0, stream>>>(Wout, wout_bf, D_MODEL, D_INNER, D_INNER);
    }

    // --- GEMM1: xz[b][e][l] = sum_d W_in[e,d] * hs[b,l,d] ---
    k_gemm<false><<<dim3(2 * D_INNER / 128, SEQLEN / 128, BATCH), 256, 0, stream>>>(
        win_bf, hs_bf, xz,
        2 * D_INNER, SEQLEN, KPAD, KPAD, KPAD, SEQLEN,
        0LL, (long long)SEQLEN * KPAD, (long long)2 * D_INNER * SEQLEN);

    // --- conv1d + silu on x half ---
    k_conv<<<(BATCH * D_INNER * SEQLEN) / 256, 256, 0, stream>>>(xz, cw, cb, xc);

    // --- transpose x_conv to (b,l,d) bf16 for token-major GEMMs ---
    k_transpose_bf16<<<dim3(D_INNER / 64, SEQLEN / 64, BATCH), 256, 0, stream>>>(xc, xct);

    // --- GEMM2: x_dbl[b][l][e] = sum_d xct[b,l,d] * W_x[e,d]  (bf16 out) ---
    k_gemm<true><<<dim3(SEQLEN / 128, 1, BATCH), 256, 0, stream>>>(
        xct, wx_bf, xdbl,
        SEQLEN, 96, D_INNER, D_INNER, D_INNER, 96,
        (long long)SEQLEN * D_INNER, 0LL, (long long)SEQLEN * 96);

    // --- GEMM3: delta_raw[b][d][l] = sum_r W_dt[d,r] * dt_lo[b,l,r] ---
    k_gemm<false><<<dim3(D_INNER / 128, SEQLEN / 128, BATCH), 256, 0, stream>>>(
        wdt_bf, xdbl, delta,
        D_INNER, SEQLEN, DT_RANK, DT_RANK, 96, SEQLEN,
        0LL, (long long)SEQLEN * 96, (long long)D_INNER * SEQLEN);

    // --- selective scan (y written in-place over delta) ---
    k_scan<<<BATCH * D_INNER / 16, 256, 0, stream>>>(delta, delta, xc, xdbl, bdt, Alog);

    // --- gate -> y_g (b,l,d) bf16 (reuses xct buffer) ---
    k_gate<<<dim3(D_INNER / 64, SEQLEN / 64, BATCH), 256, 0, stream>>>(delta, xc, xz, Dp, xct);

    // --- GEMM4: out[b][l][o] = sum_d y_g[b,l,d] * W_out[o,d] ---
    k_gemm<false><<<dim3(SEQLEN / 128, D_MODEL / 128, BATCH), 256, 0, stream>>>(
        xct, wout_bf, out,
        SEQLEN, D_MODEL, D_INNER, D_INNER, D_INNER, D_MODEL,
        (long long)SEQLEN * D_INNER, 0LL, (long long)SEQLEN * D_MODEL);
}

// Round 2
// 464.568 us; speedup vs baseline: 3.4427x; 3.4427x over previous
//
#include <hip/hip_runtime.h>
#include <hip/hip_bf16.h>
#include <stdint.h>

typedef __hip_bfloat16 bf16_t;
typedef __attribute__((ext_vector_type(4))) float f32x4;
typedef __attribute__((ext_vector_type(8))) short bf16x8;
typedef __attribute__((ext_vector_type(4))) int int4v;

#define D_MODEL 1024
#define D_INNER 2048
#define D_STATE 16
#define DT_RANK 64
#define BATCH   2
#define SEQLEN  2048
#define KPAD    1056   // 1025 padded up to multiple of 32
#define NCHUNK  8
#define CHUNK   (SEQLEN / NCHUNK)   // 256
#define NCHAN   (BATCH * D_INNER)   // 4096 channels

// ---------------- convert f32 -> bf16 with optional right-pad (zeros) -------
__global__ void k_convert_pad(const float* __restrict__ src, bf16_t* __restrict__ dst,
                              int rows, int cols, int dcols)
{
    long long idx = (long long)blockIdx.x * blockDim.x + threadIdx.x;
    long long total = (long long)rows * dcols;
    if (idx >= total) return;
    int c = (int)(idx % dcols);
    long long r = idx / dcols;
    float v = (c < cols) ? src[r * (long long)cols + c] : 0.0f;
    dst[idx] = __float2bfloat16(v);
}

// ---------------- bf16 MFMA GEMM: C[M,N] = A[M,K] * B[N,K]^T ----------------
// OUT mode: 0 = f32, 1 = bf16, 2 = dt-softplus (writes softplus(acc + bias[row]))
template<int OUT>
__global__ __launch_bounds__(256)
void k_gemm(const bf16_t* __restrict__ A, const bf16_t* __restrict__ B,
            void* __restrict__ Cv,
            int M, int N, int K, int lda, int ldb, int ldc,
            long long strideA, long long strideB, long long strideC,
            const float* __restrict__ ep_bias)
{
    const bf16_t* Ab = A + (long long)blockIdx.z * strideA;
    const bf16_t* Bb = B + (long long)blockIdx.z * strideB;

    __shared__ bf16_t As[128][40];   // +8 pad: row stride 80B (16B-aligned)
    __shared__ bf16_t Bs[128][40];

    const int tid  = threadIdx.x;
    const int lane = tid & 63;
    const int wave = tid >> 6;
    const int wm = (wave >> 1) * 64;
    const int wn = (wave & 1) * 64;
    const int bm = blockIdx.x * 128;
    const int bn = blockIdx.y * 128;

    const int srow = tid >> 2;          // 0..63
    const int sseg = (tid & 3) * 8;     // 0,8,16,24 (elements)

    f32x4 acc[4][4] = {};

    for (int k0 = 0; k0 < K; k0 += 32) {
        #pragma unroll
        for (int rr = 0; rr < 128; rr += 64) {
            int row = srow + rr;
            int ga = bm + row;
            int4v va = {0, 0, 0, 0};
            if (ga < M) va = *(const int4v*)(Ab + (long long)ga * lda + k0 + sseg);
            *(int4v*)(&As[row][sseg]) = va;
            int gb = bn + row;
            int4v vb = {0, 0, 0, 0};
            if (gb < N) vb = *(const int4v*)(Bb + (long long)gb * ldb + k0 + sseg);
            *(int4v*)(&Bs[row][sseg]) = vb;
        }
        __syncthreads();

        const int fr = lane & 15;
        const int fk = (lane >> 4) * 8;
        bf16x8 af[4], bfv[4];
        #pragma unroll
        for (int m = 0; m < 4; ++m)
            af[m] = *(const bf16x8*)(&As[wm + m * 16 + fr][fk]);
        #pragma unroll
        for (int n = 0; n < 4; ++n)
            bfv[n] = *(const bf16x8*)(&Bs[wn + n * 16 + fr][fk]);
        #pragma unroll
        for (int m = 0; m < 4; ++m)
            #pragma unroll
            for (int n = 0; n < 4; ++n)
                acc[m][n] = __builtin_amdgcn_mfma_f32_16x16x32_bf16(af[m], bfv[n], acc[m][n], 0, 0, 0);
        __syncthreads();
    }

    const int fr = lane & 15;
    const int rq = (lane >> 4) * 4;
    #pragma unroll
    for (int m = 0; m < 4; ++m) {
        #pragma unroll
        for (int n = 0; n < 4; ++n) {
            int col = bn + wn + n * 16 + fr;
            if (col >= N) continue;
            int rowb = bm + wm + m * 16 + rq;
            #pragma unroll
            for (int r = 0; r < 4; ++r) {
                long long off = (long long)blockIdx.z * strideC + (long long)(rowb + r) * ldc + col;
                if (OUT == 1) ((bf16_t*)Cv)[off] = __float2bfloat16(acc[m][n][r]);
                else if (OUT == 2) {
                    float raw = acc[m][n][r] + ep_bias[rowb + r];
                    ((float*)Cv)[off] = fmaxf(raw, 0.0f) + log1pf(__expf(-fabsf(raw)));
                } else ((float*)Cv)[off] = acc[m][n][r];
            }
        }
    }
}

// ---------------- depthwise causal conv1d (k=4) + SiLU ----------------------
__global__ void k_conv(const float* __restrict__ xz, const float* __restrict__ cw,
                       const float* __restrict__ cb, float* __restrict__ xc)
{
    long long idx = (long long)blockIdx.x * 256 + threadIdx.x;
    int t = (int)(idx & (SEQLEN - 1));
    int d = (int)((idx >> 11) & (D_INNER - 1));
    int b = (int)(idx >> 22);
    const float* xp = xz + ((long long)b * 2 * D_INNER + d) * SEQLEN;
    float a = cb[d];
    const float* w = cw + d * 4;
    #pragma unroll
    for (int j = 0; j < 4; ++j) {
        int tt = t + j - 3;
        float xv = (tt >= 0) ? xp[tt] : 0.0f;
        a = fmaf(w[j], xv, a);
    }
    xc[idx] = a / (1.0f + __expf(-a));   // SiLU
}

// ---------------- transpose (b,d,l) f32 -> (b,l,d) bf16 ---------------------
__global__ void k_transpose_bf16(const float* __restrict__ src, bf16_t* __restrict__ dst)
{
    __shared__ float tile[64][65];
    const int b  = blockIdx.z;
    const int d0 = blockIdx.x * 64;
    const int l0 = blockIdx.y * 64;
    const int tl = threadIdx.x & 63;
    const int tr = threadIdx.x >> 6;   // 0..3
    #pragma unroll
    for (int i = 0; i < 64; i += 4)
        tile[tr + i][tl] = src[((long long)b * D_INNER + d0 + tr + i) * SEQLEN + l0 + tl];
    __syncthreads();
    #pragma unroll
    for (int i = 0; i < 64; i += 4)
        dst[((long long)b * SEQLEN + l0 + tr + i) * D_INNER + d0 + tl] =
            __float2bfloat16(tile[tl][tr + i]);
}

// ---------------- gate: y_g(b,l,d) bf16 = (y + D*xc) * silu(z) --------------
// y lives in the x-half of xz: row (b*2D + d); z in row (b*2D + D + d)
__global__ void k_gate(const float* __restrict__ xz, const float* __restrict__ xc,
                       const float* __restrict__ Dp, bf16_t* __restrict__ dst)
{
    __shared__ float tile[64][65];
    const int b  = blockIdx.z;
    const int d0 = blockIdx.x * 64;
    const int l0 = blockIdx.y * 64;
    const int tl = threadIdx.x & 63;
    const int tr = threadIdx.x >> 6;
    #pragma unroll
    for (int i = 0; i < 64; i += 4) {
        int d = d0 + tr + i;
        long long offy = ((long long)b * 2 * D_INNER + d) * SEQLEN + l0 + tl;
        long long offu = ((long long)b * D_INNER + d) * SEQLEN + l0 + tl;
        float yv = xz[offy] + Dp[d] * xc[offu];
        float zv = xz[offy + (long long)D_INNER * SEQLEN];
        tile[tr + i][tl] = yv * (zv / (1.0f + __expf(-zv)));
    }
    __syncthreads();
    #pragma unroll
    for (int i = 0; i < 64; i += 4)
        dst[((long long)b * SEQLEN + l0 + tr + i) * D_INNER + d0 + tl] =
            __float2bfloat16(tile[tl][tr + i]);
}

// ---------------- chunked selective scan ------------------------------------
// 16 lanes per channel (one state n each), 16 channels per block, NCHUNK chunks.
// FINAL=false: compute h_loc (h over chunk from 0) and P = prod(dA). No y.
// FINAL=true : start from h_start[chunk], emit y (written into xz x-half).
template<bool FINAL>
__global__ __launch_bounds__(256)
void k_scan_chunk(const float* __restrict__ dt_arr, const float* __restrict__ xc,
                  const bf16_t* __restrict__ xdbl, const float* __restrict__ A_log,
                  float* __restrict__ hloc, float* __restrict__ Pout,
                  const float* __restrict__ hstart, float* __restrict__ y_xz)
{
    const int g  = threadIdx.x >> 4;       // channel within block
    const int n  = threadIdx.x & 15;       // state index
    const int bd = blockIdx.x * 16 + g;    // global channel
    const int b  = bd >> 11;
    const int d  = bd & (D_INNER - 1);
    const int ck = blockIdx.y;
    const int t0 = ck * CHUNK;

    const float An = -__expf(A_log[d * D_STATE + n]);
    const long long chan = (long long)bd * SEQLEN + t0;
    const float* dp = dt_arr + chan;
    const float* up = xc + chan;
    const bf16_t* bc = xdbl + ((long long)b * SEQLEN + t0) * 96;
    float* yp = y_xz + ((long long)b * 2 * D_INNER + d) * SEQLEN + t0;

    float h = FINAL ? hstart[((long long)ck * NCHAN + bd) * D_STATE + n] : 0.0f;
    float P = 1.0f;
    float ykeep = 0.0f;

    for (int t = 0; t < CHUNK; t += 4) {
        float4 d4 = *(const float4*)(dp + t);
        float4 u4 = *(const float4*)(up + t);
        #pragma unroll
        for (int j = 0; j < 4; ++j) {
            int tt = t + j;
            float dt = (&d4.x)[j];
            float u  = (&u4.x)[j];
            float Bn = __bfloat162float(bc[(long long)tt * 96 + 64 + n]);
            float dA = __expf(dt * An);
            h = fmaf(h, dA, dt * u * Bn);
            if (!FINAL) P *= dA;
            if (FINAL) {
                float Cn = __bfloat162float(bc[(long long)tt * 96 + 80 + n]);
                float yv = h * Cn;
                yv += __shfl_xor(yv, 1);
                yv += __shfl_xor(yv, 2);
                yv += __shfl_xor(yv, 4);
                yv += __shfl_xor(yv, 8);
                if ((tt & 15) == n) ykeep = yv;
                if ((tt & 15) == 15) yp[(tt & ~15) + n] = ykeep;
            }
        }
    }
    if (!FINAL) {
        long long o = ((long long)ck * NCHAN + bd) * D_STATE + n;
        hloc[o] = h;
        Pout[o] = P;
    }
}

// ---------------- combine chunk boundary states -----------------------------
__global__ void k_scan_combine(const float* __restrict__ hloc, const float* __restrict__ P,
                               float* __restrict__ hstart)
{
    int i = blockIdx.x * 256 + threadIdx.x;   // over NCHAN * D_STATE = 65536
    float hs = 0.0f;
    hstart[i] = 0.0f;
    #pragma unroll
    for (int c = 1; c < NCHUNK; ++c) {
        int prev = (c - 1) * (NCHAN * D_STATE) + i;
        hs = fmaf(P[prev], hs, hloc[prev]);
        hstart[c * (NCHAN * D_STATE) + i] = hs;
    }
}

// ---------------------------------------------------------------------------
extern "C" void kernel_launch(void* const* d_in, const int* in_sizes, int n_in,
                              void* d_out, int out_size, void* d_ws, size_t ws_size,
                              hipStream_t stream)
{
    const float* hs   = (const float*)d_in[0];
    const float* Win  = (const float*)d_in[1];
    const float* cw   = (const float*)d_in[2];
    const float* cb   = (const float*)d_in[3];
    const float* Wx   = (const float*)d_in[4];
    const float* Wdt  = (const float*)d_in[5];
    const float* bdt  = (const float*)d_in[6];
    const float* Alog = (const float*)d_in[7];
    const float* Dp   = (const float*)d_in[8];
    const float* Wout = (const float*)d_in[9];
    float* out = (float*)d_out;

    char* w = (char*)d_ws;
    auto alloc = [&](long long bytes) {
        char* p = w;
        w += (bytes + 255) & ~255LL;
        return p;
    };
    bf16_t* hs_bf   = (bf16_t*)alloc((long long)BATCH * SEQLEN * KPAD * 2);
    bf16_t* win_bf  = (bf16_t*)alloc((long long)2 * D_INNER * KPAD * 2);
    bf16_t* wx_bf   = (bf16_t*)alloc((long long)96 * D_INNER * 2);
    bf16_t* wdt_bf  = (bf16_t*)alloc((long long)D_INNER * DT_RANK * 2);
    bf16_t* wout_bf = (bf16_t*)alloc((long long)D_MODEL * D_INNER * 2);
    float*  xz      = (float*) alloc((long long)BATCH * 2 * D_INNER * SEQLEN * 4);
    float*  xc      = (float*) alloc((long long)BATCH * D_INNER * SEQLEN * 4);
    bf16_t* xct     = (bf16_t*)alloc((long long)BATCH * SEQLEN * D_INNER * 2); // reused as y_g
    bf16_t* xdbl    = (bf16_t*)alloc((long long)BATCH * SEQLEN * 96 * 2);
    float*  dtarr   = (float*) alloc((long long)BATCH * D_INNER * SEQLEN * 4);
    float*  hloc    = (float*) alloc((long long)NCHUNK * NCHAN * D_STATE * 4);
    float*  Pbuf    = (float*) alloc((long long)NCHUNK * NCHAN * D_STATE * 4);
    float*  hstart  = (float*) alloc((long long)NCHUNK * NCHAN * D_STATE * 4);

    // --- prep converts (f32 -> bf16, K-pad with zeros) ---
    {
        long long tot = (long long)BATCH * SEQLEN * KPAD;
        k_convert_pad<<<(unsigned)((tot + 255) / 256), 256, 0, stream>>>(hs, hs_bf, BATCH * SEQLEN, 1025, KPAD);
    }
    {
        long long tot = (long long)2 * D_INNER * KPAD;
        k_convert_pad<<<(unsigned)((tot + 255) / 256), 256, 0, stream>>>(Win, win_bf, 2 * D_INNER, 1025, KPAD);
    }
    {
        long long tot = (long long)96 * D_INNER;
        k_convert_pad<<<(unsigned)((tot + 255) / 256), 256, 0, stream>>>(Wx, wx_bf, 96, D_INNER, D_INNER);
    }
    {
        long long tot = (long long)D_INNER * DT_RANK;
        k_convert_pad<<<(unsigned)((tot + 255) / 256), 256, 0, stream>>>(Wdt, wdt_bf, D_INNER, DT_RANK, DT_RANK);
    }
    {
        long long tot = (long long)D_MODEL * D_INNER;
        k_convert_pad<<<(unsigned)((tot + 255) / 256), 256, 0, stream>>>(Wout, wout_bf, D_MODEL, D_INNER, D_INNER);
    }

    // --- GEMM1: xz[b][e][l] = sum_d W_in[e,d] * hs[b,l,d] ---
    k_gemm<0><<<dim3(2 * D_INNER / 128, SEQLEN / 128, BATCH), 256, 0, stream>>>(
        win_bf, hs_bf, xz,
        2 * D_INNER, SEQLEN, KPAD, KPAD, KPAD, SEQLEN,
        0LL, (long long)SEQLEN * KPAD, (long long)2 * D_INNER * SEQLEN, nullptr);

    // --- conv1d + silu on x half ---
    k_conv<<<(BATCH * D_INNER * SEQLEN) / 256, 256, 0, stream>>>(xz, cw, cb, xc);

    // --- transpose x_conv to (b,l,d) bf16 for token-major GEMMs ---
    k_transpose_bf16<<<dim3(D_INNER / 64, SEQLEN / 64, BATCH), 256, 0, stream>>>(xc, xct);

    // --- GEMM2: x_dbl[b][l][e] = sum_d xct[b,l,d] * W_x[e,d]  (bf16 out) ---
    k_gemm<1><<<dim3(SEQLEN / 128, 1, BATCH), 256, 0, stream>>>(
        xct, wx_bf, xdbl,
        SEQLEN, 96, D_INNER, D_INNER, D_INNER, 96,
        (long long)SEQLEN * D_INNER, 0LL, (long long)SEQLEN * 96, nullptr);

    // --- GEMM3: dt[b][d][l] = softplus(sum_r W_dt[d,r]*dt_lo[b,l,r] + b_dt[d]) ---
    k_gemm<2><<<dim3(D_INNER / 128, SEQLEN / 128, BATCH), 256, 0, stream>>>(
        wdt_bf, xdbl, dtarr,
        D_INNER, SEQLEN, DT_RANK, DT_RANK, 96, SEQLEN,
        0LL, (long long)SEQLEN * 96, (long long)D_INNER * SEQLEN, bdt);

    // --- chunked selective scan ---
    k_scan_chunk<false><<<dim3(NCHAN / 16, NCHUNK), 256, 0, stream>>>(
        dtarr, xc, xdbl, Alog, hloc, Pbuf, nullptr, xz);
    k_scan_combine<<<(NCHAN * D_STATE) / 256, 256, 0, stream>>>(hloc, Pbuf, hstart);
    k_scan_chunk<true><<<dim3(NCHAN / 16, NCHUNK), 256, 0, stream>>>(
        dtarr, xc, xdbl, Alog, nullptr, nullptr, hstart, xz);

    // --- gate -> y_g (b,l,d) bf16 (reuses xct buffer) ---
    k_gate<<<dim3(D_INNER / 64, SEQLEN / 64, BATCH), 256, 0, stream>>>(xz, xc, Dp, xct);

    // --- GEMM4: out[b][l][o] = sum_d y_g[b,l,d] * W_out[o,d] ---
    k_gemm<0><<<dim3(SEQLEN / 128, D_MODEL / 128, BATCH), 256, 0, stream>>>(
        xct, wout_bf, out,
        SEQLEN, D_MODEL, D_INNER, D_INNER, D_INNER, D_MODEL,
        (long long)SEQLEN * D_INNER, 0LL, (long long)SEQLEN * D_MODEL, nullptr);
}